// Round 8
// baseline (255.604 us; speedup 1.0000x reference)
//
#include <hip/hip_runtime.h>
#include <math.h>

// Problem constants: N=2, T=1024, D=256, W=128, H=8, HD=32
#define NTOK 2048
#define TT   1024
constexpr float SCL = 0.17677669529663687f; // 1/sqrt(32)

// ---- workspace layout (in floats) ----
// Requires ws_size >= 34,668,544 bytes (~33.1 MB)
#define OFF_WQT 0
#define OFF_WKT 65536
#define OFF_WVT 131072
#define OFF_OWT 196608
#define OFF_RQ  262144          // 2048*2048 floats (rq, [i][s*16 + h*2 + par], scaled)
#define OFF_SB  4456448         // 2048*8 floats (score bias, scaled)
#define OFF_CTX 4472832         // 2048*2048 floats (ctx, [i][k*8+h])

// async global->LDS, 16B per lane; lds dst is wave-uniform base (HW adds lane*16)
#define GLOAD_LDS16(g, l)                                                      \
    __builtin_amdgcn_global_load_lds(                                          \
        (const __attribute__((address_space(1))) unsigned int*)(g),            \
        (__attribute__((address_space(3))) unsigned int*)(l), 16, 0, 0)

// ---------------- K0: transpose Wq,Wk,Wv,out_w into ws ----------------
__global__ __launch_bounds__(256) void k0_transpose(const float* __restrict__ ipw,
                                                    const float* __restrict__ ow,
                                                    float* __restrict__ ws) {
    __shared__ float tile[32][33];
    int bx = blockIdx.x;
    int mat = bx >> 6, tl = bx & 63;
    int tr0 = (tl >> 3) << 5, tc0 = (tl & 7) << 5;
    const float* src;
    float* dst;
    if (mat == 3) { src = ow;             dst = ws + OFF_OWT; }
    else          { src = ipw + mat*65536; dst = ws + OFF_WQT + mat*65536; }
    int c = threadIdx.x & 31, r0 = threadIdx.x >> 5;
    #pragma unroll
    for (int k = 0; k < 4; k++) {
        int r = r0 + k*8;
        tile[r][c] = src[(tr0 + r)*256 + tc0 + c];
    }
    __syncthreads();
    #pragma unroll
    for (int k = 0; k < 4; k++) {
        int r = r0 + k*8;
        dst[(tc0 + r)*256 + tr0 + c] = tile[c][r];
    }
}

// ---------------- K1: qh -> rq (Wk folded into q) + score bias ----------------
__global__ __launch_bounds__(512) void k1_qrq(const float* __restrict__ x,
                                              const float* __restrict__ ipw,
                                              const float* __restrict__ ipb,
                                              float* __restrict__ ws) {
    __shared__ float x8[2048];     // 8 tokens x 256
    __shared__ float qpart[4096];  // 2 halves x 8 x 256
    __shared__ float qh[2048];     // 8 x 256
    const float* wqT = ws + OFF_WQT;
    const float* wk  = ipw + 65536;   // Wk raw: wk[r*256 + c] = Wk[r][c]
    float* rqw = ws + OFF_RQ;
    float* sbw = ws + OFF_SB;
    int tid = threadIdx.x;
    long i0 = (long)blockIdx.x * 8;

    ((float4*)x8)[tid] = ((const float4*)(x + i0*256))[tid];
    __syncthreads();

    int c = tid & 255, half = tid >> 8;
    {   // qh partials over cc-half
        float qa[8];
        #pragma unroll
        for (int ii = 0; ii < 8; ii++) qa[ii] = 0.f;
        int cc0 = half*128;
        #pragma unroll 8
        for (int cc = cc0; cc < cc0 + 128; cc++) {
            float w = wqT[cc*256 + c];
            #pragma unroll
            for (int ii = 0; ii < 8; ii++) qa[ii] += x8[ii*256 + cc]*w;
        }
        #pragma unroll
        for (int ii = 0; ii < 8; ii++) qpart[(half*8 + ii)*256 + c] = qa[ii];
    }
    __syncthreads();
    if (tid < 256) {
        float b = ipb[tid];
        #pragma unroll
        for (int ii = 0; ii < 8; ii++)
            qh[ii*256 + tid] = qpart[ii*256 + tid] + qpart[(8 + ii)*256 + tid] + b;
    }
    __syncthreads();
    {   // rq: per thread k, 4 heads.  rq[h,k] = SCL * sum_hd qh[h*32+hd] * Wk[h*32+hd, k]
        int k = tid & 255, hh = tid >> 8;
        int s = k & 127, par = k >> 7;
        for (int h = hh*4; h < hh*4 + 4; h++) {
            float ra[8];
            #pragma unroll
            for (int ii = 0; ii < 8; ii++) ra[ii] = 0.f;
            #pragma unroll 8
            for (int hd = 0; hd < 32; hd++) {
                float w = wk[(h*32 + hd)*256 + k];   // coalesced over k
                #pragma unroll
                for (int ii = 0; ii < 8; ii++) ra[ii] += qh[ii*256 + h*32 + hd]*w;
            }
            // layout: [i][s*16 + h*2 + par]  (16 consecutive floats per s)
            #pragma unroll
            for (int ii = 0; ii < 8; ii++)
                rqw[(i0 + ii)*2048 + s*16 + h*2 + par] = ra[ii]*SCL;
        }
    }
    if (tid < 64) {  // score bias = (qh . bk_h)/sqrt(32)
        int ii = tid >> 3, h = tid & 7;
        float s = 0.f;
        #pragma unroll 8
        for (int hd = 0; hd < 32; hd++) s += qh[ii*256 + h*32 + hd]*ipb[256 + h*32 + hd];
        sbw[(i0 + ii)*8 + h] = s*SCL;
    }
}

// ---------------- K2: main attention (one block per token) ----------------
// dyn LDS = 156672 B: xw[128*258] | rq2[2048] (aliased by attn[1024]) | scp[4096]
__global__ __launch_bounds__(512) void k2_attn(const float* __restrict__ x,
                                               float* __restrict__ ws) {
    extern __shared__ float sm[];
    float* xw   = sm;                  // 33024 floats, row stride 258
    float* rq2  = sm + 33024;          // 2048 floats, [s*16 + h*2 + par]
    float* scp  = sm + 33024 + 2048;   // 4096 floats
    float* attn = rq2;                 // alias (rq2 dead after scores)
    const float* rqw = ws + OFF_RQ;
    const float* sbw = ws + OFF_SB;
    float* ctxw = ws + OFF_CTX;
    int tid = threadIdx.x;
    int i = blockIdx.x;
    int t = i & (TT - 1);
    int w = tid >> 6, lane = tid & 63;

    // ---- stage window + rq via async global->LDS (1 row = 1 instruction) ----
    {
        #pragma unroll
        for (int it = 0; it < 16; it++) {
            int r = it*8 + w;                 // wave-uniform row
            int ts = t - 127 + r;
            float* lrow = xw + r*258;         // row is 1024B contiguous; pad untouched
            if (ts >= 0) {
                const float* g = x + (long)(i - 127 + r)*256 + lane*4;
                GLOAD_LDS16(g, lrow);
            } else {
                float4 z = {0.f, 0.f, 0.f, 0.f};
                *(float4*)(lrow + lane*4) = z;
            }
        }
        const float* g = rqw + (long)i*2048 + w*256 + lane*4;
        GLOAD_LDS16(g, rq2 + w*256);
    }
    __syncthreads();

    // ---- scores: thread (jj, q); per s: 4x b128 broadcast + 1x b64 ----
    {
        int jj = tid & 127, q = tid >> 7;
        float a[8];
        #pragma unroll
        for (int h = 0; h < 8; h++) a[h] = 0.f;
        const float4* rq4 = (const float4*)rq2;
        #pragma unroll 4
        for (int s = q*32; s < q*32 + 32; s++) {
            float2 x2 = *(const float2*)&xw[s*258 + 2*jj];
            float4 r0 = rq4[s*4 + 0];
            float4 r1 = rq4[s*4 + 1];
            float4 r2 = rq4[s*4 + 2];
            float4 r3 = rq4[s*4 + 3];
            a[0] += r0.x*x2.x + r0.y*x2.y;
            a[1] += r0.z*x2.x + r0.w*x2.y;
            a[2] += r1.x*x2.x + r1.y*x2.y;
            a[3] += r1.z*x2.x + r1.w*x2.y;
            a[4] += r2.x*x2.x + r2.y*x2.y;
            a[5] += r2.z*x2.x + r2.w*x2.y;
            a[6] += r3.x*x2.x + r3.y*x2.y;
            a[7] += r3.z*x2.x + r3.w*x2.y;
        }
        #pragma unroll
        for (int h = 0; h < 8; h++) scp[h*512 + q*128 + jj] = a[h];
    }
    __syncthreads();

    // ---- softmax: wave h (8 waves), lane l covers j=l and j=l+64 ----
    {
        int h = tid >> 6, l = tid & 63;
        float sb = sbw[i*8 + h];
        float s1 = sb, s2 = sb;
        #pragma unroll
        for (int q = 0; q < 4; q++) {
            s1 += scp[h*512 + q*128 + l];
            s2 += scp[h*512 + q*128 + l + 64];
        }
        int lim = 127 - t;
        bool m1 = l < lim, m2 = (l + 64) < lim;
        if (m1) s1 = -1e30f;
        if (m2) s2 = -1e30f;
        float m = fmaxf(s1, s2);
        #pragma unroll
        for (int d = 1; d < 64; d <<= 1) m = fmaxf(m, __shfl_xor(m, d, 64));
        float e1 = m1 ? 0.f : __expf(s1 - m);
        float e2 = m2 ? 0.f : __expf(s2 - m);
        float sum = e1 + e2;
        #pragma unroll
        for (int d = 1; d < 64; d <<= 1) sum += __shfl_xor(sum, d, 64);
        float r = 1.0f / sum;
        attn[l*8 + h] = e1*r;
        attn[(l + 64)*8 + h] = e2*r;
    }
    __syncthreads();

    // ---- ctx: thread (sC, jq) accumulates [p][h] (16 accs) over 32 j ----
    {
        int sC = tid & 127, jq = tid >> 7;
        float cac[16];
        #pragma unroll
        for (int c = 0; c < 16; c++) cac[c] = 0.f;
        #pragma unroll 4
        for (int j = jq*32; j < jq*32 + 32; j++) {
            float2 x2 = *(const float2*)&xw[sC*258 + 2*j];
            float4 a0 = *(const float4*)&attn[j*8];
            float4 a1 = *(const float4*)&attn[j*8 + 4];
            cac[0]  += a0.x*x2.x; cac[1]  += a0.y*x2.x; cac[2]  += a0.z*x2.x; cac[3]  += a0.w*x2.x;
            cac[4]  += a1.x*x2.x; cac[5]  += a1.y*x2.x; cac[6]  += a1.z*x2.x; cac[7]  += a1.w*x2.x;
            cac[8]  += a0.x*x2.y; cac[9]  += a0.y*x2.y; cac[10] += a0.z*x2.y; cac[11] += a0.w*x2.y;
            cac[12] += a1.x*x2.y; cac[13] += a1.y*x2.y; cac[14] += a1.z*x2.y; cac[15] += a1.w*x2.y;
        }
        __syncthreads();  // all xw reads done -> safe to overwrite xw with partials
        #pragma unroll
        for (int c = 0; c < 16; c++) xw[c*512 + tid] = cac[c];  // [c][thr], conflict-free
    }
    __syncthreads();

    // ---- reduce 4 j-quarters, write ctx[i][k*8+h] ----
    if (tid < 256) {
        int k = tid, p = k >> 7;
        float v[8];
        #pragma unroll
        for (int h = 0; h < 8; h++) v[h] = 0.f;
        #pragma unroll
        for (int jq = 0; jq < 4; jq++) {
            int thr = jq*128 + (k & 127);
            #pragma unroll
            for (int h = 0; h < 8; h++) v[h] += xw[(p*8 + h)*512 + thr];
        }
        float4* dst = (float4*)(ctxw + (long)i*2048 + k*8);
        float4 o0 = {v[0], v[1], v[2], v[3]};
        float4 o1 = {v[4], v[5], v[6], v[7]};
        dst[0] = o0; dst[1] = o1;
    }
}

// ---------------- K3: out = out_w @ (Wv_blockdiag @ ctx + bv) + out_b ----------------
// dyn LDS = 90112 B: ctx8[16384] | oppart[4096] | op[2048]
__global__ __launch_bounds__(512) void k3_proj(const float* __restrict__ ipb,
                                               const float* __restrict__ ob,
                                               float* __restrict__ ws,
                                               float* __restrict__ out) {
    extern __shared__ float sm[];
    float* ctx8   = sm;                  // 8 tokens x 2048
    float* oppart = sm + 16384;          // 2 x 8 x 256
    float* op     = sm + 16384 + 4096;   // 8 x 256
    const float* wvT  = ws + OFF_WVT;
    const float* owT  = ws + OFF_OWT;
    const float* ctxw = ws + OFF_CTX;
    int tid = threadIdx.x;
    long i0 = (long)blockIdx.x * 8;

    {
        const float4* src = (const float4*)(ctxw + i0*2048);
        float4* dst = (float4*)ctx8;
        #pragma unroll
        for (int it = 0; it < 8; it++) dst[it*512 + tid] = src[it*512 + tid];
    }
    __syncthreads();

    int c = tid & 255, kh = tid >> 8;
    {   // out_pre partials: per-head Wv fold
        int h = c >> 5;
        float acc[8];
        #pragma unroll
        for (int ii = 0; ii < 8; ii++) acc[ii] = 0.f;
        #pragma unroll 8
        for (int k = kh*128; k < kh*128 + 128; k++) {
            float w = wvT[k*256 + c];
            #pragma unroll
            for (int ii = 0; ii < 8; ii++) acc[ii] += w*ctx8[ii*2048 + k*8 + h];
        }
        #pragma unroll
        for (int ii = 0; ii < 8; ii++) oppart[(kh*8 + ii)*256 + c] = acc[ii];
    }
    __syncthreads();
    if (tid < 256) {
        float b = ipb[512 + tid];
        #pragma unroll
        for (int ii = 0; ii < 8; ii++)
            op[ii*256 + tid] = oppart[ii*256 + tid] + oppart[(8 + ii)*256 + tid] + b;
    }
    __syncthreads();
    {   // final projection partials
        float acc[8];
        #pragma unroll
        for (int ii = 0; ii < 8; ii++) acc[ii] = 0.f;
        #pragma unroll 8
        for (int cc = kh*128; cc < kh*128 + 128; cc++) {
            float w = owT[cc*256 + c];
            #pragma unroll
            for (int ii = 0; ii < 8; ii++) acc[ii] += w*op[ii*256 + cc];
        }
        #pragma unroll
        for (int ii = 0; ii < 8; ii++) oppart[(kh*8 + ii)*256 + c] = acc[ii];
    }
    __syncthreads();
    if (tid < 256) {
        float b = ob[tid];
        #pragma unroll
        for (int ii = 0; ii < 8; ii++)
            out[(i0 + ii)*256 + tid] = oppart[ii*256 + tid] + oppart[(8 + ii)*256 + tid] + b;
    }
}

extern "C" void kernel_launch(void* const* d_in, const int* in_sizes, int n_in,
                              void* d_out, int out_size, void* d_ws, size_t ws_size,
                              hipStream_t stream) {
    const float* x   = (const float*)d_in[0];   // (2,1024,256)
    const float* ipw = (const float*)d_in[1];   // (768,256)
    const float* ipb = (const float*)d_in[2];   // (768)
    const float* ow  = (const float*)d_in[3];   // (256,256)
    const float* ob  = (const float*)d_in[4];   // (256)
    float* out = (float*)d_out;
    float* ws  = (float*)d_ws;                  // needs ~33.1 MB

    (void)in_sizes; (void)n_in; (void)out_size; (void)ws_size;

    // allow >64KB dynamic LDS (idempotent; host-side, graph-capture safe)
    hipFuncSetAttribute(reinterpret_cast<const void*>(k2_attn),
                        hipFuncAttributeMaxDynamicSharedMemorySize, 156672);
    hipFuncSetAttribute(reinterpret_cast<const void*>(k3_proj),
                        hipFuncAttributeMaxDynamicSharedMemorySize, 90112);

    hipLaunchKernelGGL(k0_transpose, dim3(256),  dim3(256), 0,      stream, ipw, ow, ws);
    hipLaunchKernelGGL(k1_qrq,       dim3(256),  dim3(512), 0,      stream, x, ipw, ipb, ws);
    hipLaunchKernelGGL(k2_attn,      dim3(2048), dim3(512), 156672, stream, x, ws);
    hipLaunchKernelGGL(k3_proj,      dim3(256),  dim3(512), 90112,  stream, ipb, ob, ws, out);
}

// Round 10
// 184.589 us; speedup vs baseline: 1.3847x; 1.3847x over previous
//
#include <hip/hip_runtime.h>
#include <math.h>

// Problem constants: N=2, T=1024, D=256, W=128, H=8, HD=32
#define NTOK 2048
#define TT   1024
constexpr float SCL = 0.17677669529663687f; // 1/sqrt(32)

// ---- workspace layout (in floats) ----
// Requires ws_size >= 34,668,544 bytes (~33.1 MB)
#define OFF_WQT 0
#define OFF_WKT 65536
#define OFF_WVT 131072
#define OFF_OWT 196608
#define OFF_RQ  262144          // 2048*2048 floats (rq, [i][s*16 + h*2 + par], scaled)
#define OFF_SB  4456448         // 2048*8 floats (score bias, scaled)
#define OFF_CTX 4472832         // 2048*2048 floats (ctx, [i][k*8+h])

// async global->LDS, 16B per lane; lds dst is wave-uniform base (HW adds lane*16)
#define GLOAD_LDS16(g, l)                                                      \
    __builtin_amdgcn_global_load_lds(                                          \
        (const __attribute__((address_space(1))) unsigned int*)(g),            \
        (__attribute__((address_space(3))) unsigned int*)(l), 16, 0, 0)

// ---------------- K0: transpose Wq,Wk,Wv,out_w into ws ----------------
__global__ __launch_bounds__(256) void k0_transpose(const float* __restrict__ ipw,
                                                    const float* __restrict__ ow,
                                                    float* __restrict__ ws) {
    __shared__ float tile[32][33];
    int bx = blockIdx.x;
    int mat = bx >> 6, tl = bx & 63;
    int tr0 = (tl >> 3) << 5, tc0 = (tl & 7) << 5;
    const float* src;
    float* dst;
    if (mat == 3) { src = ow;             dst = ws + OFF_OWT; }
    else          { src = ipw + mat*65536; dst = ws + OFF_WQT + mat*65536; }
    int c = threadIdx.x & 31, r0 = threadIdx.x >> 5;
    #pragma unroll
    for (int k = 0; k < 4; k++) {
        int r = r0 + k*8;
        tile[r][c] = src[(tr0 + r)*256 + tc0 + c];
    }
    __syncthreads();
    #pragma unroll
    for (int k = 0; k < 4; k++) {
        int r = r0 + k*8;
        dst[(tc0 + r)*256 + tr0 + c] = tile[c][r];
    }
}

// ---------------- K1: qh -> rq (Wk folded into q) + score bias ----------------
// rq stores staged in LDS, flushed as coalesced float4 (R8: 10x write-amp fix).
// dyn LDS = 67584 B: rqt[8][16*132] (plane layout [ii][h2p*132 + s])
__global__ __launch_bounds__(512) void k1_qrq(const float* __restrict__ x,
                                              const float* __restrict__ ipw,
                                              const float* __restrict__ ipb,
                                              float* __restrict__ ws) {
    __shared__ float x8[2048];     // 8 tokens x 256
    __shared__ float qpart[4096];  // 2 halves x 8 x 256
    __shared__ float qh[2048];     // 8 x 256
    extern __shared__ float rqt[]; // 8 x 2112 floats
    const float* wqT = ws + OFF_WQT;
    const float* wk  = ipw + 65536;   // Wk raw: wk[r*256 + c] = Wk[r][c]
    float* rqw = ws + OFF_RQ;
    float* sbw = ws + OFF_SB;
    int tid = threadIdx.x;
    long i0 = (long)blockIdx.x * 8;

    ((float4*)x8)[tid] = ((const float4*)(x + i0*256))[tid];
    __syncthreads();

    int c = tid & 255, half = tid >> 8;
    {   // qh partials over cc-half
        float qa[8];
        #pragma unroll
        for (int ii = 0; ii < 8; ii++) qa[ii] = 0.f;
        int cc0 = half*128;
        #pragma unroll 8
        for (int cc = cc0; cc < cc0 + 128; cc++) {
            float w = wqT[cc*256 + c];
            #pragma unroll
            for (int ii = 0; ii < 8; ii++) qa[ii] += x8[ii*256 + cc]*w;
        }
        #pragma unroll
        for (int ii = 0; ii < 8; ii++) qpart[(half*8 + ii)*256 + c] = qa[ii];
    }
    __syncthreads();
    if (tid < 256) {
        float b = ipb[tid];
        #pragma unroll
        for (int ii = 0; ii < 8; ii++)
            qh[ii*256 + tid] = qpart[ii*256 + tid] + qpart[(8 + ii)*256 + tid] + b;
    }
    __syncthreads();
    {   // rq compute -> LDS tile.  rq[h,k] = SCL * sum_hd qh[h*32+hd] * Wk[h*32+hd, k]
        int k = tid & 255, hh = tid >> 8;
        int s = k & 127, par = k >> 7;
        for (int h = hh*4; h < hh*4 + 4; h++) {
            float ra[8];
            #pragma unroll
            for (int ii = 0; ii < 8; ii++) ra[ii] = 0.f;
            #pragma unroll 8
            for (int hd = 0; hd < 32; hd++) {
                float w = wk[(h*32 + hd)*256 + k];   // coalesced over k
                #pragma unroll
                for (int ii = 0; ii < 8; ii++) ra[ii] += qh[ii*256 + h*32 + hd]*w;
            }
            // LDS plane layout: [ii][ (h*2+par)*132 + s ]  (lanes walk s: conflict-free)
            int h2p = h*2 + par;
            #pragma unroll
            for (int ii = 0; ii < 8; ii++)
                rqt[ii*2112 + h2p*132 + s] = ra[ii]*SCL;
        }
    }
    __syncthreads();
    {   // flush: global layout [i][s*16 + h2p], fully coalesced float4 stores
        float4* dst = (float4*)(rqw + i0*2048);
        #pragma unroll
        for (int it = 0; it < 8; it++) {
            int f = it*512 + tid;          // ii = it (512 float4 per token)
            int s = (f & 511) >> 2, q = f & 3;
            int base = it*2112 + s;
            float4 v;
            v.x = rqt[base + (4*q + 0)*132];
            v.y = rqt[base + (4*q + 1)*132];
            v.z = rqt[base + (4*q + 2)*132];
            v.w = rqt[base + (4*q + 3)*132];
            dst[f] = v;
        }
    }
    if (tid < 64) {  // score bias = (qh . bk_h)/sqrt(32)
        int ii = tid >> 3, h = tid & 7;
        float s = 0.f;
        #pragma unroll 8
        for (int hd = 0; hd < 32; hd++) s += qh[ii*256 + h*32 + hd]*ipb[256 + h*32 + hd];
        sbw[(i0 + ii)*8 + h] = s*SCL;
    }
}

// ---------------- K2: main attention (one block per token) ----------------
// dyn LDS = 156672 B: xw[128*258] | rq2[2048] (aliased by attn[1024]) | scp[4096]
__global__ __launch_bounds__(512) void k2_attn(const float* __restrict__ x,
                                               float* __restrict__ ws) {
    extern __shared__ float sm[];
    float* xw   = sm;                  // 33024 floats, row stride 258
    float* rq2  = sm + 33024;          // 2048 floats, [s*16 + h*2 + par]
    float* scp  = sm + 33024 + 2048;   // 4096 floats
    float* attn = rq2;                 // alias (rq2 dead after scores)
    const float* rqw = ws + OFF_RQ;
    const float* sbw = ws + OFF_SB;
    float* ctxw = ws + OFF_CTX;
    int tid = threadIdx.x;
    int i = blockIdx.x;
    int t = i & (TT - 1);
    int w = tid >> 6, lane = tid & 63;

    // ---- stage window + rq via async global->LDS (1 row = 1 instruction) ----
    {
        #pragma unroll
        for (int it = 0; it < 16; it++) {
            int r = it*8 + w;                 // wave-uniform row
            int ts = t - 127 + r;
            float* lrow = xw + r*258;         // row is 1024B contiguous; pad untouched
            if (ts >= 0) {
                const float* g = x + (long)(i - 127 + r)*256 + lane*4;
                GLOAD_LDS16(g, lrow);
            } else {
                float4 z = {0.f, 0.f, 0.f, 0.f};
                *(float4*)(lrow + lane*4) = z;
            }
        }
        const float* g = rqw + (long)i*2048 + w*256 + lane*4;
        GLOAD_LDS16(g, rq2 + w*256);
    }
    __syncthreads();

    // ---- scores: thread (jj, q); per s: 4x b128 broadcast + 1x b64 ----
    {
        int jj = tid & 127, q = tid >> 7;
        float a[8];
        #pragma unroll
        for (int h = 0; h < 8; h++) a[h] = 0.f;
        const float4* rq4 = (const float4*)rq2;
        #pragma unroll 4
        for (int s = q*32; s < q*32 + 32; s++) {
            float2 x2 = *(const float2*)&xw[s*258 + 2*jj];
            float4 r0 = rq4[s*4 + 0];
            float4 r1 = rq4[s*4 + 1];
            float4 r2 = rq4[s*4 + 2];
            float4 r3 = rq4[s*4 + 3];
            a[0] += r0.x*x2.x + r0.y*x2.y;
            a[1] += r0.z*x2.x + r0.w*x2.y;
            a[2] += r1.x*x2.x + r1.y*x2.y;
            a[3] += r1.z*x2.x + r1.w*x2.y;
            a[4] += r2.x*x2.x + r2.y*x2.y;
            a[5] += r2.z*x2.x + r2.w*x2.y;
            a[6] += r3.x*x2.x + r3.y*x2.y;
            a[7] += r3.z*x2.x + r3.w*x2.y;
        }
        #pragma unroll
        for (int h = 0; h < 8; h++) scp[h*512 + q*128 + jj] = a[h];
    }
    __syncthreads();

    // ---- softmax: wave h (8 waves), lane l covers j=l and j=l+64 ----
    {
        int h = tid >> 6, l = tid & 63;
        float sb = sbw[i*8 + h];
        float s1 = sb, s2 = sb;
        #pragma unroll
        for (int q = 0; q < 4; q++) {
            s1 += scp[h*512 + q*128 + l];
            s2 += scp[h*512 + q*128 + l + 64];
        }
        int lim = 127 - t;
        bool m1 = l < lim, m2 = (l + 64) < lim;
        if (m1) s1 = -1e30f;
        if (m2) s2 = -1e30f;
        float m = fmaxf(s1, s2);
        #pragma unroll
        for (int d = 1; d < 64; d <<= 1) m = fmaxf(m, __shfl_xor(m, d, 64));
        float e1 = m1 ? 0.f : __expf(s1 - m);
        float e2 = m2 ? 0.f : __expf(s2 - m);
        float sum = e1 + e2;
        #pragma unroll
        for (int d = 1; d < 64; d <<= 1) sum += __shfl_xor(sum, d, 64);
        float r = 1.0f / sum;
        attn[l*8 + h] = e1*r;
        attn[(l + 64)*8 + h] = e2*r;
    }
    __syncthreads();

    // ---- ctx: thread (sC, jq) accumulates [p][h] (16 accs) over 32 j ----
    {
        int sC = tid & 127, jq = tid >> 7;
        float cac[16];
        #pragma unroll
        for (int c = 0; c < 16; c++) cac[c] = 0.f;
        #pragma unroll 4
        for (int j = jq*32; j < jq*32 + 32; j++) {
            float2 x2 = *(const float2*)&xw[sC*258 + 2*j];
            float4 a0 = *(const float4*)&attn[j*8];
            float4 a1 = *(const float4*)&attn[j*8 + 4];
            cac[0]  += a0.x*x2.x; cac[1]  += a0.y*x2.x; cac[2]  += a0.z*x2.x; cac[3]  += a0.w*x2.x;
            cac[4]  += a1.x*x2.x; cac[5]  += a1.y*x2.x; cac[6]  += a1.z*x2.x; cac[7]  += a1.w*x2.x;
            cac[8]  += a0.x*x2.y; cac[9]  += a0.y*x2.y; cac[10] += a0.z*x2.y; cac[11] += a0.w*x2.y;
            cac[12] += a1.x*x2.y; cac[13] += a1.y*x2.y; cac[14] += a1.z*x2.y; cac[15] += a1.w*x2.y;
        }
        __syncthreads();  // all xw reads done -> safe to overwrite xw with partials
        #pragma unroll
        for (int c = 0; c < 16; c++) xw[c*512 + tid] = cac[c];  // [c][thr], conflict-free
    }
    __syncthreads();

    // ---- reduce 4 j-quarters, write ctx[i][k*8+h] ----
    if (tid < 256) {
        int k = tid, p = k >> 7;
        float v[8];
        #pragma unroll
        for (int h = 0; h < 8; h++) v[h] = 0.f;
        #pragma unroll
        for (int jq = 0; jq < 4; jq++) {
            int thr = jq*128 + (k & 127);
            #pragma unroll
            for (int h = 0; h < 8; h++) v[h] += xw[(p*8 + h)*512 + thr];
        }
        float4* dst = (float4*)(ctxw + (long)i*2048 + k*8);
        float4 o0 = {v[0], v[1], v[2], v[3]};
        float4 o1 = {v[4], v[5], v[6], v[7]};
        dst[0] = o0; dst[1] = o1;
    }
}

// ---------------- K3: out = out_w @ (Wv_blockdiag @ ctx + bv) + out_b ----------------
// dyn LDS = 90112 B: ctx8[16384] | oppart[4096] | op[2048]
__global__ __launch_bounds__(512) void k3_proj(const float* __restrict__ ipb,
                                               const float* __restrict__ ob,
                                               float* __restrict__ ws,
                                               float* __restrict__ out) {
    extern __shared__ float sm[];
    float* ctx8   = sm;                  // 8 tokens x 2048
    float* oppart = sm + 16384;          // 2 x 8 x 256
    float* op     = sm + 16384 + 4096;   // 8 x 256
    const float* wvT  = ws + OFF_WVT;
    const float* owT  = ws + OFF_OWT;
    const float* ctxw = ws + OFF_CTX;
    int tid = threadIdx.x;
    long i0 = (long)blockIdx.x * 8;

    {
        const float4* src = (const float4*)(ctxw + i0*2048);
        float4* dst = (float4*)ctx8;
        #pragma unroll
        for (int it = 0; it < 8; it++) dst[it*512 + tid] = src[it*512 + tid];
    }
    __syncthreads();

    int c = tid & 255, kh = tid >> 8;
    {   // out_pre partials: per-head Wv fold
        int h = c >> 5;
        float acc[8];
        #pragma unroll
        for (int ii = 0; ii < 8; ii++) acc[ii] = 0.f;
        #pragma unroll 8
        for (int k = kh*128; k < kh*128 + 128; k++) {
            float w = wvT[k*256 + c];
            #pragma unroll
            for (int ii = 0; ii < 8; ii++) acc[ii] += w*ctx8[ii*2048 + k*8 + h];
        }
        #pragma unroll
        for (int ii = 0; ii < 8; ii++) oppart[(kh*8 + ii)*256 + c] = acc[ii];
    }
    __syncthreads();
    if (tid < 256) {
        float b = ipb[512 + tid];
        #pragma unroll
        for (int ii = 0; ii < 8; ii++)
            op[ii*256 + tid] = oppart[ii*256 + tid] + oppart[(8 + ii)*256 + tid] + b;
    }
    __syncthreads();
    {   // final projection partials
        float acc[8];
        #pragma unroll
        for (int ii = 0; ii < 8; ii++) acc[ii] = 0.f;
        #pragma unroll 8
        for (int cc = kh*128; cc < kh*128 + 128; cc++) {
            float w = owT[cc*256 + c];
            #pragma unroll
            for (int ii = 0; ii < 8; ii++) acc[ii] += w*op[ii*256 + cc];
        }
        #pragma unroll
        for (int ii = 0; ii < 8; ii++) oppart[(kh*8 + ii)*256 + c] = acc[ii];
    }
    __syncthreads();
    if (tid < 256) {
        float b = ob[tid];
        #pragma unroll
        for (int ii = 0; ii < 8; ii++)
            out[(i0 + ii)*256 + tid] = oppart[ii*256 + tid] + oppart[(8 + ii)*256 + tid] + b;
    }
}

extern "C" void kernel_launch(void* const* d_in, const int* in_sizes, int n_in,
                              void* d_out, int out_size, void* d_ws, size_t ws_size,
                              hipStream_t stream) {
    const float* x   = (const float*)d_in[0];   // (2,1024,256)
    const float* ipw = (const float*)d_in[1];   // (768,256)
    const float* ipb = (const float*)d_in[2];   // (768)
    const float* ow  = (const float*)d_in[3];   // (256,256)
    const float* ob  = (const float*)d_in[4];   // (256)
    float* out = (float*)d_out;
    float* ws  = (float*)d_ws;                  // needs ~33.1 MB

    (void)in_sizes; (void)n_in; (void)out_size; (void)ws_size;

    // allow >64KB dynamic LDS (idempotent; host-side, graph-capture safe)
    hipFuncSetAttribute(reinterpret_cast<const void*>(k1_qrq),
                        hipFuncAttributeMaxDynamicSharedMemorySize, 67584);
    hipFuncSetAttribute(reinterpret_cast<const void*>(k2_attn),
                        hipFuncAttributeMaxDynamicSharedMemorySize, 156672);
    hipFuncSetAttribute(reinterpret_cast<const void*>(k3_proj),
                        hipFuncAttributeMaxDynamicSharedMemorySize, 90112);

    hipLaunchKernelGGL(k0_transpose, dim3(256),  dim3(256), 0,      stream, ipw, ow, ws);
    hipLaunchKernelGGL(k1_qrq,       dim3(256),  dim3(512), 67584,  stream, x, ipw, ipb, ws);
    hipLaunchKernelGGL(k2_attn,      dim3(2048), dim3(512), 156672, stream, x, ws);
    hipLaunchKernelGGL(k3_proj,      dim3(256),  dim3(512), 90112,  stream, ipb, ob, ws, out);
}